// Round 2
// baseline (126.634 us; speedup 1.0000x reference)
//
#include <hip/hip_runtime.h>
#include <math.h>

#define N1 8192
#define N2 8192
#define NBATCH 2
#define KNN 16
#define QPW 4              // queries per wave
#define NCHUNK (N1 / 64)

// Pack p1 = xyz1 + flow1 as float4(x, y, z, |p1|^2), and f1 as float4(fx, fy, fz, 0).
__global__ __launch_bounds__(256) void pw3_prep_kernel(
    const float* __restrict__ xyz1,
    const float* __restrict__ flow1,
    float4* __restrict__ p1p,
    float4* __restrict__ f1p) {
  int i = blockIdx.x * blockDim.x + threadIdx.x;  // 0 .. B*N1-1
  if (i >= NBATCH * N1) return;
  int b = i >> 13;            // / N1
  int m = i & (N1 - 1);
  const float* x1 = xyz1 + b * 3 * N1;
  const float* f1 = flow1 + b * 3 * N1;
  float fx = f1[m], fy = f1[N1 + m], fz = f1[2 * N1 + m];
  float px = x1[m] + fx;
  float py = x1[N1 + m] + fy;
  float pz = x1[2 * N1 + m] + fz;
  float n1 = (px * px + py * py) + pz * pz;   // match reference (p1*p1).sum(-1)
  p1p[i] = make_float4(px, py, pz, n1);
  f1p[i] = make_float4(fx, fy, fz, 0.0f);
}

// One wave handles QPW=4 queries. Each 16-lane subgroup owns one query's
// sorted top-16 (dist,idx), distributed one entry per lane (sub 15 = kth).
// All 64 lanes share each candidate load; 4 distances per candidate.
__global__ __launch_bounds__(256) void pw3_knn_kernel(
    const float* __restrict__ xyz2,
    const float4* __restrict__ p1p,
    const float4* __restrict__ f1p,
    float* __restrict__ out) {
  int lane = threadIdx.x & 63;
  int sub = lane & 15;
  int mygroup = lane >> 4;
  int gwave = __builtin_amdgcn_readfirstlane(
      (int)((blockIdx.x * blockDim.x + threadIdx.x) >> 6));
  int q0 = gwave * QPW;            // first query id (global, 0..B*N2-1)
  int b = q0 >> 13;                // / N2 (QPW divides N2, no straddle)
  int n0 = q0 & (N2 - 1);

  const float* x2 = xyz2 + b * 3 * N2;
  float qx[QPW], qy[QPW], qz[QPW], qn[QPW];
  #pragma unroll
  for (int q = 0; q < QPW; ++q) {
    qx[q] = x2[n0 + q];
    qy[q] = x2[N2 + n0 + q];
    qz[q] = x2[2 * N2 + n0 + q];
    qn[q] = (qx[q] * qx[q] + qy[q] * qy[q]) + qz[q] * qz[q];
  }

  const float4* __restrict__ src = p1p + b * N1;

  float val = INFINITY;   // this lane's entry in its group's sorted top-16
  int   vidx = 0;
  float kth[QPW];
  #pragma unroll
  for (int q = 0; q < QPW; ++q) kth[q] = INFINITY;

  float4 s = src[lane];   // chunk 0
  #pragma unroll 1
  for (int c = 0; c < NCHUNK; ++c) {
    int nc = (c + 1 < NCHUNK) ? c + 1 : NCHUNK - 1;
    float4 nx = src[nc * 64 + lane];       // prefetch next chunk (reload-last on tail)
    int base = c * 64;

    float d[QPW];
    #pragma unroll
    for (int q = 0; q < QPW; ++q) {
      float dot = (s.x * qx[q] + s.y * qy[q]) + s.z * qz[q];
      d[q] = (qn[q] - 2.0f * dot) + s.w;   // reference expansion order
    }

    #pragma unroll
    for (int q = 0; q < QPW; ++q) {
      unsigned long long bal = __ballot(d[q] < kth[q]);
      if (bal) {
        do {
          int l = __ffsll(bal) - 1;
          bal &= bal - 1;
          float cd = __shfl(d[q], l);      // candidate dist (broadcast)
          int   ci = base + l;
          float pv = __shfl_up(val, 1);
          int   pi = __shfl_up(vidx, 1);
          bool lt  = cd < val;
          bool ltp = (sub > 0) && (cd < pv);
          if (mygroup == q && lt) {
            val  = ltp ? pv : cd;
            vidx = ltp ? pi : ci;
          }
        } while (bal);
        kth[q] = __shfl(val, q * 16 + 15);
      }
    }
    s = nx;
  }

  // Gather the selected flows (each lane holds one of its group's 16) and
  // reduce within each 16-lane group (xor offsets 8,4,2,1 stay in-group).
  float4 f = f1p[b * N1 + vidx];
  float fx = f.x, fy = f.y, fz = f.z;
  #pragma unroll
  for (int o = 8; o > 0; o >>= 1) {
    fx += __shfl_xor(fx, o);
    fy += __shfl_xor(fy, o);
    fz += __shfl_xor(fz, o);
  }

  if (sub == 0) {
    int q = mygroup;
    float ox = qx[0], oy = qy[0], oz = qz[0];
    #pragma unroll
    for (int t = 1; t < QPW; ++t) {
      if (q == t) { ox = qx[t]; oy = qy[t]; oz = qz[t]; }
    }
    int n = n0 + q;
    float* op = out + b * 3 * N2;
    const float inv_k = 1.0f / KNN;
    op[n]          = ox - fx * inv_k;
    op[N2 + n]     = oy - fy * inv_k;
    op[2 * N2 + n] = oz - fz * inv_k;
  }
}

extern "C" void kernel_launch(void* const* d_in, const int* in_sizes, int n_in,
                              void* d_out, int out_size, void* d_ws, size_t ws_size,
                              hipStream_t stream) {
  const float* xyz1  = (const float*)d_in[0];
  const float* xyz2  = (const float*)d_in[1];
  const float* flow1 = (const float*)d_in[2];
  float* out = (float*)d_out;

  float4* p1p = (float4*)d_ws;
  float4* f1p = (float4*)((char*)d_ws + (size_t)NBATCH * N1 * sizeof(float4));

  {
    int total = NBATCH * N1;
    int threads = 256;
    int blocks = (total + threads - 1) / threads;
    pw3_prep_kernel<<<blocks, threads, 0, stream>>>(xyz1, flow1, p1p, f1p);
  }
  {
    int total_waves = (NBATCH * N2) / QPW;   // one wave per QPW queries
    int threads = 256;                       // 4 waves per block
    int blocks = total_waves * 64 / threads;
    pw3_knn_kernel<<<blocks, threads, 0, stream>>>(xyz2, p1p, f1p, out);
  }
}

// Round 3
// 106.490 us; speedup vs baseline: 1.1892x; 1.1892x over previous
//
#include <hip/hip_runtime.h>
#include <math.h>

#define N1 8192
#define N2 8192
#define NBATCH 2
#define KNN 16
#define QPW 4              // queries per wave
#define NCHUNK (N1 / 64)

// Pack p1 = xyz1 + flow1 as float4(x, y, z, |p1|^2), and f1 as float4(fx, fy, fz, 0).
__global__ __launch_bounds__(256) void pw3_prep_kernel(
    const float* __restrict__ xyz1,
    const float* __restrict__ flow1,
    float4* __restrict__ p1p,
    float4* __restrict__ f1p) {
  int i = blockIdx.x * blockDim.x + threadIdx.x;  // 0 .. B*N1-1
  if (i >= NBATCH * N1) return;
  int b = i >> 13;            // / N1
  int m = i & (N1 - 1);
  const float* x1 = xyz1 + b * 3 * N1;
  const float* f1 = flow1 + b * 3 * N1;
  float fx = f1[m], fy = f1[N1 + m], fz = f1[2 * N1 + m];
  float px = x1[m] + fx;
  float py = x1[N1 + m] + fy;
  float pz = x1[2 * N1 + m] + fz;
  float n1 = (px * px + py * py) + pz * pz;   // match reference (p1*p1).sum(-1)
  p1p[i] = make_float4(px, py, pz, n1);
  f1p[i] = make_float4(fx, fy, fz, 0.0f);
}

// DPP shift-up-by-1 within each 16-lane row (row_shr:1). Lanes 0/16/32/48
// receive `old` (we pass -INF so the "candidate < prev" test is false there).
__device__ __forceinline__ float dpp_up1_f(float x, float old_v) {
  int r = __builtin_amdgcn_update_dpp(
      __builtin_bit_cast(int, old_v), __builtin_bit_cast(int, x),
      0x111, 0xf, 0xf, false);
  return __builtin_bit_cast(float, r);
}
__device__ __forceinline__ int dpp_up1_i(int x) {
  return __builtin_amdgcn_update_dpp(0, x, 0x111, 0xf, 0xf, false);
}

// One wave handles QPW=4 queries. Each 16-lane subgroup owns one query's
// sorted top-16 (dist,idx), one entry per lane, ascending (sub 15 = kth).
// Inserts are pure-VALU: DPP row_shr:1 shift + readlane broadcast.
__global__ __launch_bounds__(256) void pw3_knn_kernel(
    const float* __restrict__ xyz2,
    const float4* __restrict__ p1p,
    const float4* __restrict__ f1p,
    float* __restrict__ out) {
  int lane = threadIdx.x & 63;
  int sub = lane & 15;
  int mygroup = lane >> 4;
  int gwave = (int)((blockIdx.x * blockDim.x + threadIdx.x) >> 6);
  int q0 = gwave * QPW;            // first query id (global, 0..B*N2-1)
  int b = q0 >> 13;                // / N2 (QPW divides N2, no straddle)
  int n0 = q0 & (N2 - 1);

  const float* x2 = xyz2 + b * 3 * N2;
  float qx[QPW], qy[QPW], qz[QPW], qn[QPW];
  #pragma unroll
  for (int q = 0; q < QPW; ++q) {
    qx[q] = x2[n0 + q];
    qy[q] = x2[N2 + n0 + q];
    qz[q] = x2[2 * N2 + n0 + q];
    qn[q] = (qx[q] * qx[q] + qy[q] * qy[q]) + qz[q] * qz[q];
  }

  const float4* __restrict__ src = p1p + b * N1;

  float val = INFINITY;   // this lane's entry in its group's sorted top-16
  int   vidx = 0;
  float kth[QPW];
  bool  ing[QPW];
  #pragma unroll
  for (int q = 0; q < QPW; ++q) {
    kth[q] = INFINITY;
    ing[q] = (mygroup == q);
  }
  const float NEG_INF = -INFINITY;

  float4 s = src[lane];   // chunk 0
  #pragma unroll 1
  for (int c = 0; c < NCHUNK; ++c) {
    int nc = (c + 1 < NCHUNK) ? c + 1 : NCHUNK - 1;
    float4 nx = src[nc * 64 + lane];       // prefetch next chunk (reload-last on tail)
    int base = c * 64;

    float d[QPW];
    #pragma unroll
    for (int q = 0; q < QPW; ++q) {
      float dot = (s.x * qx[q] + s.y * qy[q]) + s.z * qz[q];
      d[q] = (qn[q] - 2.0f * dot) + s.w;   // reference expansion order
    }

    #pragma unroll
    for (int q = 0; q < QPW; ++q) {
      unsigned long long bal = __ballot(d[q] < kth[q]);
      if (bal) {
        int di = __builtin_bit_cast(int, d[q]);
        do {
          int l = __ffsll(bal) - 1;
          bal &= bal - 1;
          // candidate (dist, idx): wave-uniform scalars
          float cd = __builtin_bit_cast(float, __builtin_amdgcn_readlane(di, l));
          int   ci = base + l;
          float pv = dpp_up1_f(val, NEG_INF);   // prev lane's entry (-INF at sub==0)
          int   pi = dpp_up1_i(vidx);
          bool lt  = cd < val;
          bool ltp = cd < pv;
          bool upd = ing[q] & lt;
          val  = upd ? (ltp ? pv : cd) : val;
          vidx = upd ? (ltp ? pi : ci) : vidx;
        } while (bal);
        kth[q] = __builtin_bit_cast(
            float, __builtin_amdgcn_readlane(__builtin_bit_cast(int, val),
                                             q * 16 + 15));
      }
    }
    s = nx;
  }

  // Gather the selected flows (each lane holds one of its group's 16) and
  // reduce within each 16-lane group (xor offsets 8,4,2,1 stay in-group).
  float4 f = f1p[b * N1 + vidx];
  float fx = f.x, fy = f.y, fz = f.z;
  #pragma unroll
  for (int o = 8; o > 0; o >>= 1) {
    fx += __shfl_xor(fx, o);
    fy += __shfl_xor(fy, o);
    fz += __shfl_xor(fz, o);
  }

  if (sub == 0) {
    int q = mygroup;
    float ox = qx[0], oy = qy[0], oz = qz[0];
    #pragma unroll
    for (int t = 1; t < QPW; ++t) {
      if (q == t) { ox = qx[t]; oy = qy[t]; oz = qz[t]; }
    }
    int n = n0 + q;
    float* op = out + b * 3 * N2;
    const float inv_k = 1.0f / KNN;
    op[n]          = ox - fx * inv_k;
    op[N2 + n]     = oy - fy * inv_k;
    op[2 * N2 + n] = oz - fz * inv_k;
  }
}

extern "C" void kernel_launch(void* const* d_in, const int* in_sizes, int n_in,
                              void* d_out, int out_size, void* d_ws, size_t ws_size,
                              hipStream_t stream) {
  const float* xyz1  = (const float*)d_in[0];
  const float* xyz2  = (const float*)d_in[1];
  const float* flow1 = (const float*)d_in[2];
  float* out = (float*)d_out;

  float4* p1p = (float4*)d_ws;
  float4* f1p = (float4*)((char*)d_ws + (size_t)NBATCH * N1 * sizeof(float4));

  {
    int total = NBATCH * N1;
    int threads = 256;
    int blocks = (total + threads - 1) / threads;
    pw3_prep_kernel<<<blocks, threads, 0, stream>>>(xyz1, flow1, p1p, f1p);
  }
  {
    int total_waves = (NBATCH * N2) / QPW;   // one wave per QPW queries
    int threads = 256;                       // 4 waves per block
    int blocks = total_waves * 64 / threads;
    pw3_knn_kernel<<<blocks, threads, 0, stream>>>(xyz2, p1p, f1p, out);
  }
}